// Round 9
// baseline (345.854 us; speedup 1.0000x reference)
//
#include <hip/hip_runtime.h>
#include <math.h>

#define NN 50000
#define NE 800000
#define SLOPE 0.2f
#define NB 49        // ceil(50000 / 1024)
#define GEMMB 782    // ceil(50000 / 64) gemm blocks per side
#define EDGEB 3125   // ceil(800000 / 256) edge-parallel blocks

// ---------------- shared gemm body (used by both fused launches) ----------------
// 64 nodes x 128 cols per block, LDS-staged (round-0 proven structure; the
// no-LDS variant measured 3x slower). One call does x@W+b for one weight set.

__device__ __forceinline__ void gemm_body(int bx, const float* __restrict__ x,
                                          const float* __restrict__ W,
                                          const float* __restrict__ bptr,
                                          float* __restrict__ optr,
                                          float* xs, float* wsm) {
  int tid = threadIdx.x;
  int cx = tid & 31;   // col quad
  int rn = tid >> 5;   // node octet
  int n0 = bx * 64;

  float acc[8][4];
#pragma unroll
  for (int i = 0; i < 8; ++i)
#pragma unroll
    for (int j = 0; j < 4; ++j) acc[i][j] = 0.f;

  for (int kb = 0; kb < 128; kb += 64) {
#pragma unroll
    for (int r = 0; r < 4; ++r) {
      int q = tid + r * 256;
      int n = q >> 4, k4 = q & 15;
      float4 v = make_float4(0.f, 0.f, 0.f, 0.f);
      int gn = n0 + n;
      if (gn < NN) v = *(const float4*)(x + (size_t)gn * 128 + kb + 4 * k4);
      *(float4*)&xs[n * 68 + 4 * k4] = v;
    }
#pragma unroll
    for (int r = 0; r < 8; ++r) {
      int q = tid + r * 256;
      int kk = q >> 5, c4 = q & 31;
      float4 wv = *(const float4*)(W + (size_t)(kb + kk) * 128 + 4 * c4);
      *(float4*)&wsm[kk * 128 + 4 * c4] = wv;
    }
    __syncthreads();
#pragma unroll 2
    for (int k4 = 0; k4 < 16; ++k4) {
      float4 wv[4];
#pragma unroll
      for (int kk = 0; kk < 4; ++kk)
        wv[kk] = *(const float4*)&wsm[(4 * k4 + kk) * 128 + 4 * cx];
#pragma unroll
      for (int i = 0; i < 8; ++i) {
        float4 xv = *(const float4*)&xs[(8 * rn + i) * 68 + 4 * k4];
        acc[i][0] = fmaf(xv.x, wv[0].x, acc[i][0]);
        acc[i][1] = fmaf(xv.x, wv[0].y, acc[i][1]);
        acc[i][2] = fmaf(xv.x, wv[0].z, acc[i][2]);
        acc[i][3] = fmaf(xv.x, wv[0].w, acc[i][3]);
        acc[i][0] = fmaf(xv.y, wv[1].x, acc[i][0]);
        acc[i][1] = fmaf(xv.y, wv[1].y, acc[i][1]);
        acc[i][2] = fmaf(xv.y, wv[1].z, acc[i][2]);
        acc[i][3] = fmaf(xv.y, wv[1].w, acc[i][3]);
        acc[i][0] = fmaf(xv.z, wv[2].x, acc[i][0]);
        acc[i][1] = fmaf(xv.z, wv[2].y, acc[i][1]);
        acc[i][2] = fmaf(xv.z, wv[2].z, acc[i][2]);
        acc[i][3] = fmaf(xv.z, wv[2].w, acc[i][3]);
        acc[i][0] = fmaf(xv.w, wv[3].x, acc[i][0]);
        acc[i][1] = fmaf(xv.w, wv[3].y, acc[i][1]);
        acc[i][2] = fmaf(xv.w, wv[3].z, acc[i][2]);
        acc[i][3] = fmaf(xv.w, wv[3].w, acc[i][3]);
      }
    }
    __syncthreads();
  }

  int cc = 4 * cx;
  float4 bv = *(const float4*)(bptr + cc);
#pragma unroll
  for (int i = 0; i < 8; ++i) {
    int gn = n0 + 8 * rn + i;
    if (gn < NN) {
      float4 o = make_float4(acc[i][0] + bv.x, acc[i][1] + bv.y,
                             acc[i][2] + bv.z, acc[i][3] + bv.w);
      *(float4*)(optr + (size_t)gn * 128 + cc) = o;
    }
  }
}

// ---------------- fused launch A: gemm_L blocks first, then deg+rank ----------------
// deg's atomicAdd RETURNS the edge's rank among same-target edges -- persist it
// so the later scatter needs no atomic at all (pos = rowptr[t] + rank[e]).
// gemm_L rides along to hide the atomic latency.

__launch_bounds__(256)
__global__ void fusedA_kernel(const float* __restrict__ x,
                              const float* __restrict__ W_l, const float* __restrict__ b_l,
                              float* __restrict__ x_l,
                              const int* __restrict__ tgt, int* __restrict__ deg,
                              int* __restrict__ rank) {
  __shared__ float xs[64 * 68];
  __shared__ float wsm[64 * 128];
  if (blockIdx.x < GEMMB) {
    gemm_body(blockIdx.x, x, W_l, b_l, x_l, xs, wsm);
  } else {
    int e = (blockIdx.x - GEMMB) * 256 + threadIdx.x;
    if (e < NE) rank[e] = atomicAdd(&deg[tgt[e]], 1);
  }
}

// ---------------- fused launch B: gemm_R blocks first, then atomic-free scatter ----
// scatter + attr gather: pos is computed (rowptr[tgt] + rank), so every load
// issues immediately and the 68B payload stores have no atomic on their
// dependence chain -- pure streaming with full MLP.

__launch_bounds__(256)
__global__ void fusedB_kernel(const float* __restrict__ x,
                              const float* __restrict__ W_r, const float* __restrict__ b_r,
                              float* __restrict__ x_r,
                              const int* __restrict__ src, const int* __restrict__ tgt,
                              const int* __restrict__ rank,
                              const int* __restrict__ rowptr,
                              const float4* __restrict__ eattr4,
                              int* __restrict__ csr_src,
                              float4* __restrict__ eattr_csr4) {
  __shared__ float xs[64 * 68];
  __shared__ float wsm[64 * 128];
  if (blockIdx.x < GEMMB) {
    gemm_body(blockIdx.x, x, W_r, b_r, x_r, xs, wsm);
  } else {
    int e = (blockIdx.x - GEMMB) * 256 + threadIdx.x;
    if (e < NE) {
      int t = tgt[e];
      int r = rank[e];
      float4 a0 = eattr4[(size_t)e * 4 + 0];
      float4 a1 = eattr4[(size_t)e * 4 + 1];
      float4 a2 = eattr4[(size_t)e * 4 + 2];
      float4 a3 = eattr4[(size_t)e * 4 + 3];
      int pos = rowptr[t] + r;
      csr_src[pos] = src[e];
      eattr_csr4[(size_t)pos * 4 + 0] = a0;
      eattr_csr4[(size_t)pos * 4 + 1] = a1;
      eattr_csr4[(size_t)pos * 4 + 2] = a2;
      eattr_csr4[(size_t)pos * 4 + 3] = a3;
    }
  }
}

// ---------------- CSR prefix-scan (2 kernels; scanpart folded into final) ----------

__global__ void partial_kernel(const int* __restrict__ deg, int* __restrict__ psum) {
  int b = blockIdx.x;
  int base = b * 1024 + threadIdx.x * 4;
  int s = 0;
  if (base + 3 < NN) {
    int4 v = *(const int4*)(deg + base);
    s = v.x + v.y + v.z + v.w;
  } else {
#pragma unroll
    for (int i = 0; i < 4; ++i)
      if (base + i < NN) s += deg[base + i];
  }
  s += __shfl_xor(s, 1);
  s += __shfl_xor(s, 2);
  s += __shfl_xor(s, 4);
  s += __shfl_xor(s, 8);
  s += __shfl_xor(s, 16);
  s += __shfl_xor(s, 32);
  __shared__ int wsum[4];
  if ((threadIdx.x & 63) == 0) wsum[threadIdx.x >> 6] = s;
  __syncthreads();
  if (threadIdx.x == 0) psum[b] = wsum[0] + wsum[1] + wsum[2] + wsum[3];
}

// Each block redundantly wave-scans the 49 psums (cheap) -> no separate
// scanpart launch, no serialization point. Block 0 writes the grand total.
__global__ void final_kernel(const int* __restrict__ deg, const int* __restrict__ psum,
                             int* __restrict__ rowptr) {
  __shared__ int offs_s;
  __shared__ int wtot[4];
  int b = blockIdx.x;
  int t = threadIdx.x;
  if (t < 64) {
    int lane = t;
    int mine = (lane < NB) ? psum[lane] : 0;
    int v = mine;
#pragma unroll
    for (int off = 1; off < 64; off <<= 1) {
      int u = __shfl_up(v, off);
      if (lane >= off) v += u;
    }
    if (lane == b) offs_s = v - mine;          // this block's exclusive offset
    if (b == 0 && lane == 63) rowptr[NN] = v;  // grand total
  }
  __syncthreads();

  int base = b * 1024 + t * 4;
  int d0 = 0, d1 = 0, d2 = 0, d3 = 0;
  if (base + 3 < NN) {
    int4 v = *(const int4*)(deg + base);
    d0 = v.x; d1 = v.y; d2 = v.z; d3 = v.w;
  } else {
    if (base < NN) d0 = deg[base];
    if (base + 1 < NN) d1 = deg[base + 1];
    if (base + 2 < NN) d2 = deg[base + 2];
  }
  int s = d0 + d1 + d2 + d3;
  int lane = t & 63, w = t >> 6;
  int v = s;
#pragma unroll
  for (int off = 1; off < 64; off <<= 1) {
    int u = __shfl_up(v, off);
    if (lane >= off) v += u;
  }
  if (lane == 63) wtot[w] = v;
  __syncthreads();
  int woff = 0;
#pragma unroll
  for (int i = 0; i < 4; ++i)
    if (i < w) woff += wtot[i];
  int run = offs_s + woff + (v - s);
  if (base < NN)     { rowptr[base] = run;     run += d0; }
  if (base + 1 < NN) { rowptr[base + 1] = run; run += d1; }
  if (base + 2 < NN) { rowptr[base + 2] = run; run += d2; }
  if (base + 3 < NN) { rowptr[base + 3] = run; }
}

// ---------------- main GATv2 kernel (byte-identical to rounds 7-8) ----------------
// One wave per 4 consecutive targets. lane L holds channels (2L, 2L+1);
// head h = L>>4. Attr rows pre-gathered into CSR order -> induction-based
// s_loads; 4-wide edge loop for x_l-gather MLP (round-7: 107.6 -> 101.2 us).

#define EDGE_PROC(AV, XL)                                              \
  {                                                                    \
    float e0 = AV[0] * wek[0].x;                                       \
    e0 = fmaf(AV[1], wek[1].x, e0);   e0 = fmaf(AV[2], wek[2].x, e0);  \
    e0 = fmaf(AV[3], wek[3].x, e0);   e0 = fmaf(AV[4], wek[4].x, e0);  \
    e0 = fmaf(AV[5], wek[5].x, e0);   e0 = fmaf(AV[6], wek[6].x, e0);  \
    e0 = fmaf(AV[7], wek[7].x, e0);   e0 = fmaf(AV[8], wek[8].x, e0);  \
    e0 = fmaf(AV[9], wek[9].x, e0);   e0 = fmaf(AV[10], wek[10].x, e0);\
    e0 = fmaf(AV[11], wek[11].x, e0); e0 = fmaf(AV[12], wek[12].x, e0);\
    e0 = fmaf(AV[13], wek[13].x, e0); e0 = fmaf(AV[14], wek[14].x, e0);\
    e0 = fmaf(AV[15], wek[15].x, e0);                                  \
    float e1 = AV[0] * wek[0].y;                                       \
    e1 = fmaf(AV[1], wek[1].y, e1);   e1 = fmaf(AV[2], wek[2].y, e1);  \
    e1 = fmaf(AV[3], wek[3].y, e1);   e1 = fmaf(AV[4], wek[4].y, e1);  \
    e1 = fmaf(AV[5], wek[5].y, e1);   e1 = fmaf(AV[6], wek[6].y, e1);  \
    e1 = fmaf(AV[7], wek[7].y, e1);   e1 = fmaf(AV[8], wek[8].y, e1);  \
    e1 = fmaf(AV[9], wek[9].y, e1);   e1 = fmaf(AV[10], wek[10].y, e1);\
    e1 = fmaf(AV[11], wek[11].y, e1); e1 = fmaf(AV[12], wek[12].y, e1);\
    e1 = fmaf(AV[13], wek[13].y, e1); e1 = fmaf(AV[14], wek[14].y, e1);\
    e1 = fmaf(AV[15], wek[15].y, e1);                                  \
    es0 += e0; es1 += e1;                                              \
    float m0 = (XL.x + xr.x) + e0;                                     \
    float m1 = (XL.y + xr.y) + e1;                                     \
    float lm0 = fmaf(SLOPE, fminf(m0, 0.f), fmaxf(m0, 0.f));           \
    float lm1 = fmaf(SLOPE, fminf(m1, 0.f), fmaxf(m1, 0.f));           \
    float part = fmaf(attv.y, lm1, attv.x * lm0);                      \
    part += __shfl_xor(part, 1);                                       \
    part += __shfl_xor(part, 2);                                       \
    part += __shfl_xor(part, 4);                                       \
    part += __shfl_xor(part, 8);                                       \
    float p = __expf(part);                                            \
    lh += p;                                                           \
    acc0 = fmaf(p, XL.x, acc0);                                        \
    acc1 = fmaf(p, XL.y, acc1);                                        \
  }

__launch_bounds__(256)
__global__ void gat_kernel(const float* __restrict__ x_l, const float* __restrict__ x_r,
                           const int* __restrict__ rowptr, const int* __restrict__ csr_src,
                           const float* __restrict__ eattr_csr, const float* __restrict__ W_e,
                           const float* __restrict__ att, const float* __restrict__ bias,
                           float* __restrict__ out) {
  int wid = threadIdx.x >> 6;
  int lane = threadIdx.x & 63;
  int tbase = (blockIdx.x * 4 + wid) * 4;  // 3125*4*4 == 50000

  float2 wek[16];
#pragma unroll
  for (int k = 0; k < 16; ++k)
    wek[k] = *(const float2*)(W_e + k * 128 + 2 * lane);
  float2 attv = *(const float2*)(att + 2 * lane);
  float bv = bias[(2 * lane) & 31];
  float bv1 = bias[((2 * lane) & 31) + 1];

  for (int tt = 0; tt < 4; ++tt) {
    int t = tbase + tt;
    float2 xr = *(const float2*)(x_r + (size_t)t * 128 + 2 * lane);
    int start = __builtin_amdgcn_readfirstlane(rowptr[t]);
    int end = __builtin_amdgcn_readfirstlane(rowptr[t + 1]);

    float lh = 0.f, acc0 = 0.f, acc1 = 0.f, es0 = 0.f, es1 = 0.f;

    int j = start;
    for (; j + 4 <= end; j += 4) {
      int s0 = __builtin_amdgcn_readfirstlane(csr_src[j]);
      int s1 = __builtin_amdgcn_readfirstlane(csr_src[j + 1]);
      int s2 = __builtin_amdgcn_readfirstlane(csr_src[j + 2]);
      int s3 = __builtin_amdgcn_readfirstlane(csr_src[j + 3]);
      float2 xl0 = *(const float2*)(x_l + (size_t)s0 * 128 + 2 * lane);
      float2 xl1 = *(const float2*)(x_l + (size_t)s1 * 128 + 2 * lane);
      float2 xl2 = *(const float2*)(x_l + (size_t)s2 * 128 + 2 * lane);
      float2 xl3 = *(const float2*)(x_l + (size_t)s3 * 128 + 2 * lane);
      const float* ap0 = eattr_csr + (size_t)j * 16;
      {
        float a0[16];
#pragma unroll
        for (int k = 0; k < 16; ++k) a0[k] = ap0[k];
        EDGE_PROC(a0, xl0)
      }
      {
        float a1[16];
#pragma unroll
        for (int k = 0; k < 16; ++k) a1[k] = ap0[16 + k];
        EDGE_PROC(a1, xl1)
      }
      {
        float a2[16];
#pragma unroll
        for (int k = 0; k < 16; ++k) a2[k] = ap0[32 + k];
        EDGE_PROC(a2, xl2)
      }
      {
        float a3[16];
#pragma unroll
        for (int k = 0; k < 16; ++k) a3[k] = ap0[48 + k];
        EDGE_PROC(a3, xl3)
      }
    }
    if (j + 2 <= end) {
      int s0 = __builtin_amdgcn_readfirstlane(csr_src[j]);
      int s1 = __builtin_amdgcn_readfirstlane(csr_src[j + 1]);
      float2 xl0 = *(const float2*)(x_l + (size_t)s0 * 128 + 2 * lane);
      float2 xl1 = *(const float2*)(x_l + (size_t)s1 * 128 + 2 * lane);
      const float* ap0 = eattr_csr + (size_t)j * 16;
      {
        float a0[16];
#pragma unroll
        for (int k = 0; k < 16; ++k) a0[k] = ap0[k];
        EDGE_PROC(a0, xl0)
      }
      {
        float a1[16];
#pragma unroll
        for (int k = 0; k < 16; ++k) a1[k] = ap0[16 + k];
        EDGE_PROC(a1, xl1)
      }
      j += 2;
    }
    if (j < end) {
      int srcn = __builtin_amdgcn_readfirstlane(csr_src[j]);
      const float* ap = eattr_csr + (size_t)j * 16;
      float aC[16];
#pragma unroll
      for (int k = 0; k < 16; ++k) aC[k] = ap[k];
      float2 xlC = *(const float2*)(x_l + (size_t)srcn * 128 + 2 * lane);
      EDGE_PROC(aC, xlC)
    }

    // self-loop: e = es / max(deg,1); message source is x_l[t]
    {
      float rdeg = 1.0f / fmaxf((float)(end - start), 1.0f);
      float e0 = es0 * rdeg, e1 = es1 * rdeg;
      float2 xl = *(const float2*)(x_l + (size_t)t * 128 + 2 * lane);
      float m0 = (xl.x + xr.x) + e0;
      float m1 = (xl.y + xr.y) + e1;
      float lm0 = fmaf(SLOPE, fminf(m0, 0.f), fmaxf(m0, 0.f));
      float lm1 = fmaf(SLOPE, fminf(m1, 0.f), fmaxf(m1, 0.f));
      float part = fmaf(attv.y, lm1, attv.x * lm0);
      part += __shfl_xor(part, 1);
      part += __shfl_xor(part, 2);
      part += __shfl_xor(part, 4);
      part += __shfl_xor(part, 8);
      float p = __expf(part);
      lh += p;
      acc0 = fmaf(p, xl.x, acc0);
      acc1 = fmaf(p, xl.y, acc1);
    }

    float inv = 1.0f / lh;
    float v0 = acc0 * inv, v1 = acc1 * inv;
    v0 += __shfl_xor(v0, 16);
    v0 += __shfl_xor(v0, 32);
    v1 += __shfl_xor(v1, 16);
    v1 += __shfl_xor(v1, 32);
    if (lane < 16) {
      float o0 = fmaf(v0, 0.25f, bv);
      float o1 = fmaf(v1, 0.25f, bv1);
      o0 = fmaf(SLOPE, fminf(o0, 0.f), fmaxf(o0, 0.f));
      o1 = fmaf(SLOPE, fminf(o1, 0.f), fmaxf(o1, 0.f));
      *(float2*)(out + (size_t)t * 32 + 2 * lane) = make_float2(o0, o1);
    }
  }
}

// ---------------- launch ----------------

extern "C" void kernel_launch(void* const* d_in, const int* in_sizes, int n_in,
                              void* d_out, int out_size, void* d_ws, size_t ws_size,
                              hipStream_t stream) {
  const float* x = (const float*)d_in[0];
  const int* ei = (const int*)d_in[1];
  const float* eattr = (const float*)d_in[2];
  const float* W_l = (const float*)d_in[3];
  const float* b_l = (const float*)d_in[4];
  const float* W_r = (const float*)d_in[5];
  const float* b_r = (const float*)d_in[6];
  const float* W_e = (const float*)d_in[7];
  const float* att = (const float*)d_in[8];
  const float* bias = (const float*)d_in[9];
  float* out = (float*)d_out;

  char* ws = (char*)d_ws;
  int* csr_src = (int*)ws;                       // 3,200,000 B
  float* eattr_csr = (float*)(ws + 3200000);     // 51,200,000 B
  float* x_l = (float*)(ws + 54400000);          // 25,600,000 B
  float* x_r = (float*)(ws + 80000000);          // 25,600,000 B
  int* deg = (int*)(ws + 105600000);             // 200,000 B
  int* rowptr = (int*)(ws + 105800000);          // 200,004 B
  int* rank = (int*)(ws + 106000016);            // 3,200,000 B
  int* psum = (int*)(ws + 109200016);            // 196 B

  hipMemsetAsync(deg, 0, NN * sizeof(int), stream);
  fusedA_kernel<<<GEMMB + EDGEB, 256, 0, stream>>>(x, W_l, b_l, x_l, ei + NE, deg, rank);
  partial_kernel<<<NB, 256, 0, stream>>>(deg, psum);
  final_kernel<<<NB, 256, 0, stream>>>(deg, psum, rowptr);
  fusedB_kernel<<<GEMMB + EDGEB, 256, 0, stream>>>(
      x, W_r, b_r, x_r, ei, ei + NE, rank, rowptr, (const float4*)eattr,
      csr_src, (float4*)eattr_csr);
  gat_kernel<<<NN / 16, 256, 0, stream>>>(x_l, x_r, rowptr, csr_src, eattr_csr, W_e, att, bias, out);
}

// Round 10
// 308.474 us; speedup vs baseline: 1.1212x; 1.1212x over previous
//
#include <hip/hip_runtime.h>
#include <math.h>

#define NN 50000
#define NE 800000
#define SLOPE 0.2f
#define NB 49        // ceil(50000 / 1024)
#define GEMMB 782    // ceil(50000 / 64) gemm blocks per side
#define EDGEB 3125   // ceil(800000 / 256) edge-parallel blocks

typedef __attribute__((ext_vector_type(8))) short bf16x8;
typedef __attribute__((ext_vector_type(4))) float f32x4;

// split fp32 into two bf16 halves: v ~= hi + lo, residual ~2^-16 * |v|.
// v - float(hi) is exact (same sign/exponent, Sterbenz).
static __device__ __forceinline__ void split_bf16(float v, unsigned short& h,
                                                  unsigned short& l) {
  unsigned u = __float_as_uint(v);
  h = (unsigned short)(u >> 16);
  float hf = __uint_as_float(((unsigned)h) << 16);
  float r = v - hf;
  l = (unsigned short)(__float_as_uint(r) >> 16);
}

// ---------------- MFMA split-bf16 gemm body ----------------
// 64 nodes x 128 cols per block, K=128 in 4 chunks of 32. 4 waves, each owns a
// 16-row strip. C = xh@wh + xl@wh + xh@wl on the matrix pipe (MfmaUtil was 0.0
// while the fp32 path burned 2048 VALU fmaf/thread). LDS 30.7 KB (was 50).
// Fragment layouts (m89-verified C/D; standard CDNA A/B):
//   A: row=lane&15, k=8*(lane>>4)+i   B: col=lane&15, same k
//   C: col=lane&15, row=4*(lane>>4)+reg

__device__ __forceinline__ void gemm_body(int bx, const float* __restrict__ x,
                                          const float* __restrict__ W,
                                          const float* __restrict__ bptr,
                                          float* __restrict__ optr,
                                          unsigned short* xh_s, unsigned short* xl_s,
                                          unsigned short* wh_s, unsigned short* wl_s) {
  int tid = threadIdx.x;
  int w = tid >> 6;
  int l = tid & 63;
  int n0 = bx * 64;

  f32x4 acc[8];
#pragma unroll
  for (int i = 0; i < 8; ++i) acc[i] = (f32x4){0.f, 0.f, 0.f, 0.f};

  for (int kb = 0; kb < 128; kb += 32) {
    // stage x chunk (64 rows x 32 k) as split-bf16, row stride 40 (pad)
    {
      int row = tid >> 2;
      int kc = (tid & 3) * 8;
      int gn = n0 + row;
      float4 v0 = make_float4(0.f, 0.f, 0.f, 0.f);
      float4 v1 = make_float4(0.f, 0.f, 0.f, 0.f);
      if (gn < NN) {
        v0 = *(const float4*)(x + (size_t)gn * 128 + kb + kc);
        v1 = *(const float4*)(x + (size_t)gn * 128 + kb + kc + 4);
      }
      unsigned short h[8], lo[8];
      split_bf16(v0.x, h[0], lo[0]); split_bf16(v0.y, h[1], lo[1]);
      split_bf16(v0.z, h[2], lo[2]); split_bf16(v0.w, h[3], lo[3]);
      split_bf16(v1.x, h[4], lo[4]); split_bf16(v1.y, h[5], lo[5]);
      split_bf16(v1.z, h[6], lo[6]); split_bf16(v1.w, h[7], lo[7]);
      bf16x8 hv, lv;
#pragma unroll
      for (int i = 0; i < 8; ++i) { hv[i] = (short)h[i]; lv[i] = (short)lo[i]; }
      *(bf16x8*)&xh_s[row * 40 + kc] = hv;
      *(bf16x8*)&xl_s[row * 40 + kc] = lv;
    }
    // stage W chunk TRANSPOSED (col-major for B frags), stride 40
    {
      int col = tid & 127;
      int kk0 = (tid >> 7) * 16;
      unsigned short h[16], lo[16];
#pragma unroll
      for (int j = 0; j < 16; ++j)
        split_bf16(W[(size_t)(kb + kk0 + j) * 128 + col], h[j], lo[j]);
      bf16x8 hv0, hv1, lv0, lv1;
#pragma unroll
      for (int i = 0; i < 8; ++i) {
        hv0[i] = (short)h[i]; hv1[i] = (short)h[8 + i];
        lv0[i] = (short)lo[i]; lv1[i] = (short)lo[8 + i];
      }
      *(bf16x8*)&wh_s[col * 40 + kk0] = hv0;
      *(bf16x8*)&wh_s[col * 40 + kk0 + 8] = hv1;
      *(bf16x8*)&wl_s[col * 40 + kk0] = lv0;
      *(bf16x8*)&wl_s[col * 40 + kk0 + 8] = lv1;
    }
    __syncthreads();

    int r16 = 16 * w + (l & 15);
    int ko = (l >> 4) * 8;
    bf16x8 ah = *(bf16x8*)&xh_s[r16 * 40 + ko];
    bf16x8 al = *(bf16x8*)&xl_s[r16 * 40 + ko];
#pragma unroll
    for (int ct = 0; ct < 8; ++ct) {
      int cbase = (ct * 16 + (l & 15)) * 40 + ko;
      bf16x8 bh = *(bf16x8*)&wh_s[cbase];
      bf16x8 bl = *(bf16x8*)&wl_s[cbase];
      acc[ct] = __builtin_amdgcn_mfma_f32_16x16x32_bf16(ah, bh, acc[ct], 0, 0, 0);
      acc[ct] = __builtin_amdgcn_mfma_f32_16x16x32_bf16(al, bh, acc[ct], 0, 0, 0);
      acc[ct] = __builtin_amdgcn_mfma_f32_16x16x32_bf16(ah, bl, acc[ct], 0, 0, 0);
    }
    __syncthreads();
  }

  // epilogue: lane covers col=l&15, rows 4*(l>>4)+r within the wave's strip
  int colb = l & 15;
  int rq = (l >> 4) * 4;
#pragma unroll
  for (int ct = 0; ct < 8; ++ct) {
    float bvv = bptr[ct * 16 + colb];
#pragma unroll
    for (int r = 0; r < 4; ++r) {
      int gn = n0 + 16 * w + rq + r;
      if (gn < NN) optr[(size_t)gn * 128 + ct * 16 + colb] = acc[ct][r] + bvv;
    }
  }
}

// ---------------- fused launch A: gemm_L (MFMA) + deg/rank ----------------

__launch_bounds__(256)
__global__ void fusedA_kernel(const float* __restrict__ x,
                              const float* __restrict__ W_l, const float* __restrict__ b_l,
                              float* __restrict__ x_l,
                              const int* __restrict__ tgt, int* __restrict__ deg,
                              int* __restrict__ rank) {
  __shared__ unsigned short xh_s[64 * 40], xl_s[64 * 40];
  __shared__ unsigned short wh_s[128 * 40], wl_s[128 * 40];
  if (blockIdx.x < GEMMB) {
    gemm_body(blockIdx.x, x, W_l, b_l, x_l, xh_s, xl_s, wh_s, wl_s);
  } else {
    int e = (blockIdx.x - GEMMB) * 256 + threadIdx.x;
    if (e < NE) rank[e] = atomicAdd(&deg[tgt[e]], 1);
  }
}

// ---------------- fused launch B: gemm_R (MFMA) + atomic-free scatter ----------------

__launch_bounds__(256)
__global__ void fusedB_kernel(const float* __restrict__ x,
                              const float* __restrict__ W_r, const float* __restrict__ b_r,
                              float* __restrict__ x_r,
                              const int* __restrict__ src, const int* __restrict__ tgt,
                              const int* __restrict__ rank,
                              const int* __restrict__ rowptr,
                              const float4* __restrict__ eattr4,
                              int* __restrict__ csr_src,
                              float4* __restrict__ eattr_csr4) {
  __shared__ unsigned short xh_s[64 * 40], xl_s[64 * 40];
  __shared__ unsigned short wh_s[128 * 40], wl_s[128 * 40];
  if (blockIdx.x < GEMMB) {
    gemm_body(blockIdx.x, x, W_r, b_r, x_r, xh_s, xl_s, wh_s, wl_s);
  } else {
    int e = (blockIdx.x - GEMMB) * 256 + threadIdx.x;
    if (e < NE) {
      int t = tgt[e];
      int r = rank[e];
      float4 a0 = eattr4[(size_t)e * 4 + 0];
      float4 a1 = eattr4[(size_t)e * 4 + 1];
      float4 a2 = eattr4[(size_t)e * 4 + 2];
      float4 a3 = eattr4[(size_t)e * 4 + 3];
      int pos = rowptr[t] + r;
      csr_src[pos] = src[e];
      eattr_csr4[(size_t)pos * 4 + 0] = a0;
      eattr_csr4[(size_t)pos * 4 + 1] = a1;
      eattr_csr4[(size_t)pos * 4 + 2] = a2;
      eattr_csr4[(size_t)pos * 4 + 3] = a3;
    }
  }
}

// ---------------- CSR prefix-scan (2 kernels) ----------------

__global__ void partial_kernel(const int* __restrict__ deg, int* __restrict__ psum) {
  int b = blockIdx.x;
  int base = b * 1024 + threadIdx.x * 4;
  int s = 0;
  if (base + 3 < NN) {
    int4 v = *(const int4*)(deg + base);
    s = v.x + v.y + v.z + v.w;
  } else {
#pragma unroll
    for (int i = 0; i < 4; ++i)
      if (base + i < NN) s += deg[base + i];
  }
  s += __shfl_xor(s, 1);
  s += __shfl_xor(s, 2);
  s += __shfl_xor(s, 4);
  s += __shfl_xor(s, 8);
  s += __shfl_xor(s, 16);
  s += __shfl_xor(s, 32);
  __shared__ int wsum[4];
  if ((threadIdx.x & 63) == 0) wsum[threadIdx.x >> 6] = s;
  __syncthreads();
  if (threadIdx.x == 0) psum[b] = wsum[0] + wsum[1] + wsum[2] + wsum[3];
}

// Each block redundantly wave-scans the 49 psums -> no separate scanpart launch.
__global__ void final_kernel(const int* __restrict__ deg, const int* __restrict__ psum,
                             int* __restrict__ rowptr) {
  __shared__ int offs_s;
  __shared__ int wtot[4];
  int b = blockIdx.x;
  int t = threadIdx.x;
  if (t < 64) {
    int lane = t;
    int mine = (lane < NB) ? psum[lane] : 0;
    int v = mine;
#pragma unroll
    for (int off = 1; off < 64; off <<= 1) {
      int u = __shfl_up(v, off);
      if (lane >= off) v += u;
    }
    if (lane == b) offs_s = v - mine;          // this block's exclusive offset
    if (b == 0 && lane == 63) rowptr[NN] = v;  // grand total
  }
  __syncthreads();

  int base = b * 1024 + t * 4;
  int d0 = 0, d1 = 0, d2 = 0, d3 = 0;
  if (base + 3 < NN) {
    int4 v = *(const int4*)(deg + base);
    d0 = v.x; d1 = v.y; d2 = v.z; d3 = v.w;
  } else {
    if (base < NN) d0 = deg[base];
    if (base + 1 < NN) d1 = deg[base + 1];
    if (base + 2 < NN) d2 = deg[base + 2];
  }
  int s = d0 + d1 + d2 + d3;
  int lane = t & 63, w = t >> 6;
  int v = s;
#pragma unroll
  for (int off = 1; off < 64; off <<= 1) {
    int u = __shfl_up(v, off);
    if (lane >= off) v += u;
  }
  if (lane == 63) wtot[w] = v;
  __syncthreads();
  int woff = 0;
#pragma unroll
  for (int i = 0; i < 4; ++i)
    if (i < w) woff += wtot[i];
  int run = offs_s + woff + (v - s);
  if (base < NN)     { rowptr[base] = run;     run += d0; }
  if (base + 1 < NN) { rowptr[base + 1] = run; run += d1; }
  if (base + 2 < NN) { rowptr[base + 2] = run; run += d2; }
  if (base + 3 < NN) { rowptr[base + 3] = run; }
}

// ---------------- main GATv2 kernel (byte-identical to rounds 7-9) ----------------

#define EDGE_PROC(AV, XL)                                              \
  {                                                                    \
    float e0 = AV[0] * wek[0].x;                                       \
    e0 = fmaf(AV[1], wek[1].x, e0);   e0 = fmaf(AV[2], wek[2].x, e0);  \
    e0 = fmaf(AV[3], wek[3].x, e0);   e0 = fmaf(AV[4], wek[4].x, e0);  \
    e0 = fmaf(AV[5], wek[5].x, e0);   e0 = fmaf(AV[6], wek[6].x, e0);  \
    e0 = fmaf(AV[7], wek[7].x, e0);   e0 = fmaf(AV[8], wek[8].x, e0);  \
    e0 = fmaf(AV[9], wek[9].x, e0);   e0 = fmaf(AV[10], wek[10].x, e0);\
    e0 = fmaf(AV[11], wek[11].x, e0); e0 = fmaf(AV[12], wek[12].x, e0);\
    e0 = fmaf(AV[13], wek[13].x, e0); e0 = fmaf(AV[14], wek[14].x, e0);\
    e0 = fmaf(AV[15], wek[15].x, e0);                                  \
    float e1 = AV[0] * wek[0].y;                                       \
    e1 = fmaf(AV[1], wek[1].y, e1);   e1 = fmaf(AV[2], wek[2].y, e1);  \
    e1 = fmaf(AV[3], wek[3].y, e1);   e1 = fmaf(AV[4], wek[4].y, e1);  \
    e1 = fmaf(AV[5], wek[5].y, e1);   e1 = fmaf(AV[6], wek[6].y, e1);  \
    e1 = fmaf(AV[7], wek[7].y, e1);   e1 = fmaf(AV[8], wek[8].y, e1);  \
    e1 = fmaf(AV[9], wek[9].y, e1);   e1 = fmaf(AV[10], wek[10].y, e1);\
    e1 = fmaf(AV[11], wek[11].y, e1); e1 = fmaf(AV[12], wek[12].y, e1);\
    e1 = fmaf(AV[13], wek[13].y, e1); e1 = fmaf(AV[14], wek[14].y, e1);\
    e1 = fmaf(AV[15], wek[15].y, e1);                                  \
    es0 += e0; es1 += e1;                                              \
    float m0 = (XL.x + xr.x) + e0;                                     \
    float m1 = (XL.y + xr.y) + e1;                                     \
    float lm0 = fmaf(SLOPE, fminf(m0, 0.f), fmaxf(m0, 0.f));           \
    float lm1 = fmaf(SLOPE, fminf(m1, 0.f), fmaxf(m1, 0.f));           \
    float part = fmaf(attv.y, lm1, attv.x * lm0);                      \
    part += __shfl_xor(part, 1);                                       \
    part += __shfl_xor(part, 2);                                       \
    part += __shfl_xor(part, 4);                                       \
    part += __shfl_xor(part, 8);                                       \
    float p = __expf(part);                                            \
    lh += p;                                                           \
    acc0 = fmaf(p, XL.x, acc0);                                        \
    acc1 = fmaf(p, XL.y, acc1);                                        \
  }

__launch_bounds__(256)
__global__ void gat_kernel(const float* __restrict__ x_l, const float* __restrict__ x_r,
                           const int* __restrict__ rowptr, const int* __restrict__ csr_src,
                           const float* __restrict__ eattr_csr, const float* __restrict__ W_e,
                           const float* __restrict__ att, const float* __restrict__ bias,
                           float* __restrict__ out) {
  int wid = threadIdx.x >> 6;
  int lane = threadIdx.x & 63;
  int tbase = (blockIdx.x * 4 + wid) * 4;  // 3125*4*4 == 50000

  float2 wek[16];
#pragma unroll
  for (int k = 0; k < 16; ++k)
    wek[k] = *(const float2*)(W_e + k * 128 + 2 * lane);
  float2 attv = *(const float2*)(att + 2 * lane);
  float bv = bias[(2 * lane) & 31];
  float bv1 = bias[((2 * lane) & 31) + 1];

  for (int tt = 0; tt < 4; ++tt) {
    int t = tbase + tt;
    float2 xr = *(const float2*)(x_r + (size_t)t * 128 + 2 * lane);
    int start = __builtin_amdgcn_readfirstlane(rowptr[t]);
    int end = __builtin_amdgcn_readfirstlane(rowptr[t + 1]);

    float lh = 0.f, acc0 = 0.f, acc1 = 0.f, es0 = 0.f, es1 = 0.f;

    int j = start;
    for (; j + 4 <= end; j += 4) {
      int s0 = __builtin_amdgcn_readfirstlane(csr_src[j]);
      int s1 = __builtin_amdgcn_readfirstlane(csr_src[j + 1]);
      int s2 = __builtin_amdgcn_readfirstlane(csr_src[j + 2]);
      int s3 = __builtin_amdgcn_readfirstlane(csr_src[j + 3]);
      float2 xl0 = *(const float2*)(x_l + (size_t)s0 * 128 + 2 * lane);
      float2 xl1 = *(const float2*)(x_l + (size_t)s1 * 128 + 2 * lane);
      float2 xl2 = *(const float2*)(x_l + (size_t)s2 * 128 + 2 * lane);
      float2 xl3 = *(const float2*)(x_l + (size_t)s3 * 128 + 2 * lane);
      const float* ap0 = eattr_csr + (size_t)j * 16;
      {
        float a0[16];
#pragma unroll
        for (int k = 0; k < 16; ++k) a0[k] = ap0[k];
        EDGE_PROC(a0, xl0)
      }
      {
        float a1[16];
#pragma unroll
        for (int k = 0; k < 16; ++k) a1[k] = ap0[16 + k];
        EDGE_PROC(a1, xl1)
      }
      {
        float a2[16];
#pragma unroll
        for (int k = 0; k < 16; ++k) a2[k] = ap0[32 + k];
        EDGE_PROC(a2, xl2)
      }
      {
        float a3[16];
#pragma unroll
        for (int k = 0; k < 16; ++k) a3[k] = ap0[48 + k];
        EDGE_PROC(a3, xl3)
      }
    }
    if (j + 2 <= end) {
      int s0 = __builtin_amdgcn_readfirstlane(csr_src[j]);
      int s1 = __builtin_amdgcn_readfirstlane(csr_src[j + 1]);
      float2 xl0 = *(const float2*)(x_l + (size_t)s0 * 128 + 2 * lane);
      float2 xl1 = *(const float2*)(x_l + (size_t)s1 * 128 + 2 * lane);
      const float* ap0 = eattr_csr + (size_t)j * 16;
      {
        float a0[16];
#pragma unroll
        for (int k = 0; k < 16; ++k) a0[k] = ap0[k];
        EDGE_PROC(a0, xl0)
      }
      {
        float a1[16];
#pragma unroll
        for (int k = 0; k < 16; ++k) a1[k] = ap0[16 + k];
        EDGE_PROC(a1, xl1)
      }
      j += 2;
    }
    if (j < end) {
      int srcn = __builtin_amdgcn_readfirstlane(csr_src[j]);
      const float* ap = eattr_csr + (size_t)j * 16;
      float aC[16];
#pragma unroll
      for (int k = 0; k < 16; ++k) aC[k] = ap[k];
      float2 xlC = *(const float2*)(x_l + (size_t)srcn * 128 + 2 * lane);
      EDGE_PROC(aC, xlC)
    }

    // self-loop: e = es / max(deg,1); message source is x_l[t]
    {
      float rdeg = 1.0f / fmaxf((float)(end - start), 1.0f);
      float e0 = es0 * rdeg, e1 = es1 * rdeg;
      float2 xl = *(const float2*)(x_l + (size_t)t * 128 + 2 * lane);
      float m0 = (xl.x + xr.x) + e0;
      float m1 = (xl.y + xr.y) + e1;
      float lm0 = fmaf(SLOPE, fminf(m0, 0.f), fmaxf(m0, 0.f));
      float lm1 = fmaf(SLOPE, fminf(m1, 0.f), fmaxf(m1, 0.f));
      float part = fmaf(attv.y, lm1, attv.x * lm0);
      part += __shfl_xor(part, 1);
      part += __shfl_xor(part, 2);
      part += __shfl_xor(part, 4);
      part += __shfl_xor(part, 8);
      float p = __expf(part);
      lh += p;
      acc0 = fmaf(p, xl.x, acc0);
      acc1 = fmaf(p, xl.y, acc1);
    }

    float inv = 1.0f / lh;
    float v0 = acc0 * inv, v1 = acc1 * inv;
    v0 += __shfl_xor(v0, 16);
    v0 += __shfl_xor(v0, 32);
    v1 += __shfl_xor(v1, 16);
    v1 += __shfl_xor(v1, 32);
    if (lane < 16) {
      float o0 = fmaf(v0, 0.25f, bv);
      float o1 = fmaf(v1, 0.25f, bv1);
      o0 = fmaf(SLOPE, fminf(o0, 0.f), fmaxf(o0, 0.f));
      o1 = fmaf(SLOPE, fminf(o1, 0.f), fmaxf(o1, 0.f));
      *(float2*)(out + (size_t)t * 32 + 2 * lane) = make_float2(o0, o1);
    }
  }
}

// ---------------- launch ----------------

extern "C" void kernel_launch(void* const* d_in, const int* in_sizes, int n_in,
                              void* d_out, int out_size, void* d_ws, size_t ws_size,
                              hipStream_t stream) {
  const float* x = (const float*)d_in[0];
  const int* ei = (const int*)d_in[1];
  const float* eattr = (const float*)d_in[2];
  const float* W_l = (const float*)d_in[3];
  const float* b_l = (const float*)d_in[4];
  const float* W_r = (const float*)d_in[5];
  const float* b_r = (const float*)d_in[6];
  const float* W_e = (const float*)d_in[7];
  const float* att = (const float*)d_in[8];
  const float* bias = (const float*)d_in[9];
  float* out = (float*)d_out;

  char* ws = (char*)d_ws;
  int* csr_src = (int*)ws;                       // 3,200,000 B
  float* eattr_csr = (float*)(ws + 3200000);     // 51,200,000 B
  float* x_l = (float*)(ws + 54400000);          // 25,600,000 B
  float* x_r = (float*)(ws + 80000000);          // 25,600,000 B
  int* deg = (int*)(ws + 105600000);             // 200,000 B
  int* rowptr = (int*)(ws + 105800000);          // 200,004 B
  int* rank = (int*)(ws + 106000016);            // 3,200,000 B
  int* psum = (int*)(ws + 109200016);            // 196 B

  hipMemsetAsync(deg, 0, NN * sizeof(int), stream);
  fusedA_kernel<<<GEMMB + EDGEB, 256, 0, stream>>>(x, W_l, b_l, x_l, ei + NE, deg, rank);
  partial_kernel<<<NB, 256, 0, stream>>>(deg, psum);
  final_kernel<<<NB, 256, 0, stream>>>(deg, psum, rowptr);
  fusedB_kernel<<<GEMMB + EDGEB, 256, 0, stream>>>(
      x, W_r, b_r, x_r, ei, ei + NE, rank, rowptr, (const float4*)eattr,
      csr_src, (float4*)eattr_csr);
  gat_kernel<<<NN / 16, 256, 0, stream>>>(x_l, x_r, rowptr, csr_src, eattr_csr, W_e, att, bias, out);
}